// Round 1
// baseline (466.312 us; speedup 1.0000x reference)
//
#include <hip/hip_runtime.h>

#define N_NODES 50000
#define N_EDGES 800000
#define DIM     128
#define NGRAPH  128
#define NCLASS  10
#define NLAYER  4

#define TEAMS   256
#define ESLICE  (N_EDGES / TEAMS)    // 3125 edges per team slice
#define CWORDS  12500                // 50000 nodes / 4 (nibble-packed bytes per word)

// Feature-chunked layout: 4 chunks x 32 features. Each chunk's table is
// 50000 * 64 B = 3.2 MB < 4 MB per-XCD L2 -> gathers become L2-resident.
#define NCHUNK   4
#define CH_UINTS (N_NODES * 16)      // uints per chunk region (16 uints = 32 feats)
#define NHALF    (N_NODES / 2)       // 25000

typedef __attribute__((ext_vector_type(8))) short short8;
typedef __attribute__((ext_vector_type(4))) float floatx4;

__device__ __forceinline__ unsigned f2bf(float f) {
    union { float f; unsigned u; } v; v.f = f;
    return (v.u + 0x7fffu + ((v.u >> 16) & 1u)) >> 16;   // RNE
}
__device__ __forceinline__ float bf_lo(unsigned u) { return __uint_as_float(u << 16); }
__device__ __forceinline__ float bf_hi(unsigned u) { return __uint_as_float(u & 0xffff0000u); }

// ---------------------------------------------------------------------------
// Pass 1: per-team-slice nibble histograms (in=low nibble, out=high nibble,
// one byte per node). Each edge read exactly once. Coalesced writeback.
__global__ __launch_bounds__(1024) void count_kernel(
    const int* __restrict__ ei, unsigned* __restrict__ cntw)
{
    __shared__ unsigned h[CWORDS];      // 50 KB
    int team = blockIdx.x, tid = threadIdx.x;
    for (int i = tid; i < CWORDS; i += 1024) h[i] = 0;
    __syncthreads();
    const int e0 = team * ESLICE;
    const int* __restrict__ srcp = ei;
    const int* __restrict__ dstp = ei + N_EDGES;
    for (int e = e0 + tid; e < e0 + ESLICE; e += 1024) {
        int s = srcp[e], d = dstp[e];
        atomicAdd(&h[d >> 2], 1u  << (8 * (d & 3)));   // in-count  (low nibble)
        atomicAdd(&h[s >> 2], 16u << (8 * (s & 3)));   // out-count (high nibble)
    }
    __syncthreads();
    for (int i = tid; i < CWORDS; i += 1024)
        cntw[(size_t)team * CWORDS + i] = h[i];
}

// Pass 2: per-node exclusive prefix over the 256 team counts -> exact slot
// offsets; also emits total degrees -> cnt_dense, c_src, c_dst.
__global__ __launch_bounds__(1024) void offsets_kernel(
    const unsigned* __restrict__ cntw, unsigned* __restrict__ offsw,
    unsigned* __restrict__ cnt_dense, float* __restrict__ c_src,
    float* __restrict__ c_dst)
{
    __shared__ unsigned ldsC[128 * 64];   // counts tile
    __shared__ unsigned ldsO[128 * 64];   // offsets tile
    int tid = threadIdx.x;
    int n0 = blockIdx.x * 256;
    int w0 = n0 >> 2;
    unsigned indeg = 0, outdeg = 0;
    for (int ph = 0; ph < 2; ++ph) {
        int t0 = ph * 128;
        for (int i = tid; i < 128 * 64; i += 1024) {
            int tl = i >> 6, wl = i & 63;
            int gw = w0 + wl;
            ldsC[i] = (gw < CWORDS) ? cntw[(size_t)(t0 + tl) * CWORDS + gw] : 0u;
        }
        __syncthreads();
        if (tid < 256) {
            unsigned char* ob = (unsigned char*)ldsO;
            for (int tl = 0; tl < 128; ++tl) {
                unsigned wv = ldsC[tl * 64 + (tid >> 2)];
                unsigned b = (wv >> (8 * (tid & 3))) & 255u;
                ob[tl * 256 + tid] = (unsigned char)indeg;  // exclusive prefix
                indeg  += (b & 15u);
                outdeg += (b >> 4);
            }
        }
        __syncthreads();
        for (int i = tid; i < 128 * 64; i += 1024) {
            int tl = i >> 6, wl = i & 63;
            int gw = w0 + wl;
            if (gw < CWORDS) offsw[(size_t)(t0 + tl) * CWORDS + gw] = ldsO[i];
        }
        __syncthreads();
    }
    if (tid < 256) {
        int n = n0 + tid;
        if (n < N_NODES) {
            unsigned id_ = indeg, od = outdeg;
            cnt_dense[n] = id_ > 64u ? 64u : id_;
            if (id_ < 1u) id_ = 1u;
            if (od < 1u) od = 1u;
            c_dst[n] = 1.0f / sqrtf((float)id_);
            c_src[n] = 1.0f / sqrtf((float)od);
        }
    }
}

// Pass 3: rescan slice, LDS position counters give unique local pos; write
// src directly into dense CSR at offs(team,d)+pos. colc is ushort (N<65536).
__global__ __launch_bounds__(1024) void scatter_kernel(
    const int* __restrict__ ei, const unsigned* __restrict__ offsw,
    unsigned short* __restrict__ colc)
{
    __shared__ unsigned h[CWORDS];      // 50 KB pos counters (low nibble)
    int team = blockIdx.x, tid = threadIdx.x;
    for (int i = tid; i < CWORDS; i += 1024) h[i] = 0;
    __syncthreads();
    const unsigned char* __restrict__ ob =
        (const unsigned char*)offsw + (size_t)team * 50000;
    const int e0 = team * ESLICE;
    const int* __restrict__ srcp = ei;
    const int* __restrict__ dstp = ei + N_EDGES;
    for (int e = e0 + tid; e < e0 + ESLICE; e += 1024) {
        int s = srcp[e], d = dstp[e];
        unsigned old = atomicAdd(&h[d >> 2], 1u << (8 * (d & 3)));
        unsigned pos = (old >> (8 * (d & 3))) & 15u;
        unsigned slot = (unsigned)ob[d] + pos;
        if (slot < 64u) colc[(size_t)d * 64 + slot] = (unsigned short)s;
    }
}

// hs(bf16 pairs, chunk-major) = x * c_src[row]
__global__ __launch_bounds__(256) void prescale_kernel(
    const float2* __restrict__ x, const float* __restrict__ c_src,
    unsigned* __restrict__ hs)
{
    int i = blockIdx.x * blockDim.x + threadIdx.x;   // over N*64 uints
    if (i >= N_NODES * 64) return;
    int node = i >> 6, r = i & 63;
    int ch = r >> 4, u = r & 15;        // feats 2r,2r+1 = ch*32+2u, +1
    float c = c_src[node];
    float2 v = x[i];
    hs[(size_t)ch * CH_UINTS + node * 16 + u] =
        f2bf(v.x * c) | (f2bf(v.y * c) << 16);
}

// m[n] = sum over in-edges of hs[src], feature-chunked & XCD-pinned:
// block b -> xcd = b&7; chunk = xcd>>1; node-half = xcd&1. Each XCD gathers
// 25.6 MB against its 3.2 MB L2-resident chunk (~87% hit by construction).
// Octet o (8 lanes) handles one edge; lane reads uint2 = 4 feats (64 B/row
// per octet, coalesced). Cross-octet shfl_xor combine at the end.
__global__ __launch_bounds__(256) void aggregate_kernel(
    const unsigned* __restrict__ hs, const unsigned short* __restrict__ colc,
    const unsigned* __restrict__ cnt_dense, unsigned* __restrict__ m)
{
    int b = blockIdx.x;
    int grp = b & 7;                   // intended XCD id
    int ch = grp >> 1, nh = grp & 1;
    int wid = (b >> 3) * 4 + (threadIdx.x >> 6);   // 0..1023 within group
    int lane = threadIdx.x & 63;
    int o = lane >> 3, ol = lane & 7;
    const unsigned* __restrict__ hc = hs + (size_t)ch * CH_UINTS;
    unsigned* __restrict__ mc = m + (size_t)ch * CH_UINTS;
    int nbeg = nh * NHALF, nend = nbeg + NHALF;
    for (int n = nbeg + wid; n < nend; n += 1024) {
        unsigned deg = cnt_dense[n];
        int myidx = (int)__builtin_nontemporal_load(&colc[(size_t)n * 64 + lane]);
        float f0 = 0.f, f1 = 0.f, f2 = 0.f, f3 = 0.f;
        for (unsigned j = 0; j < deg; j += 16) {
#pragma unroll
            for (int k = 0; k < 2; ++k) {
                unsigned e = j + 8 * k + o;
                int sl = (e < deg) ? (int)e : 0;   // slot 0 always valid if deg>0
                int s = __shfl(myidx, sl);
                uint2 u = *(const uint2*)(hc + (size_t)s * 16 + ol * 2);
                if (e >= deg) { u.x = 0u; u.y = 0u; }
                f0 += bf_lo(u.x); f1 += bf_hi(u.x);
                f2 += bf_lo(u.y); f3 += bf_hi(u.y);
            }
        }
        f0 += __shfl_xor(f0, 8);  f1 += __shfl_xor(f1, 8);
        f2 += __shfl_xor(f2, 8);  f3 += __shfl_xor(f3, 8);
        f0 += __shfl_xor(f0, 16); f1 += __shfl_xor(f1, 16);
        f2 += __shfl_xor(f2, 16); f3 += __shfl_xor(f3, 16);
        f0 += __shfl_xor(f0, 32); f1 += __shfl_xor(f1, 32);
        f2 += __shfl_xor(f2, 32); f3 += __shfl_xor(f3, 32);
        if (o == 0) {
            unsigned* p = mc + (size_t)n * 16 + ol * 2;
            __builtin_nontemporal_store(f2bf(f0) | (f2bf(f1) << 16), p);
            __builtin_nontemporal_store(f2bf(f2) | (f2bf(f3) << 16), p + 1);
        }
    }
}

// Pre-swizzle W into MFMA B-fragment order, bf16.
__global__ __launch_bounds__(256) void wprep_kernel(
    const float* __restrict__ W0, const float* __restrict__ Ws,
    uint4* __restrict__ Wf)
{
    int t = blockIdx.x * blockDim.x + threadIdx.x;
    if (t >= NLAYER * 2048) return;
    int layer = t >> 11;
    int rem = t & 2047;
    int lane = rem & 63;
    int s = (rem >> 6) & 3;
    int c = rem >> 8;
    int quad = lane >> 4, colw = c * 16 + (lane & 15);
    int k0 = s * 32 + quad * 8;
    const float* W = (layer == 0) ? W0 : Ws + (size_t)(layer - 1) * DIM * DIM;
    uint4 p;
    unsigned* pp = (unsigned*)&p;
#pragma unroll
    for (int j = 0; j < 4; ++j) {
        unsigned lo = f2bf(W[(size_t)(k0 + 2 * j) * DIM + colw]);
        unsigned hi = f2bf(W[(size_t)(k0 + 2 * j + 1) * DIM + colw]);
        pp[j] = lo | (hi << 16);
    }
    Wf[t] = p;
}

// Hout = relu(c_dst[r]*(M@W) + b) [* c_src[r] if !last], MFMA 16x16x32 bf16.
// M is chunk-major: chunk s = K-slice s*32 -> A-fragment load of 16 rows x
// 64 B chunk is a contiguous, fully-coalesced 1 KB.
__global__ __launch_bounds__(256) void mfma_gemm_kernel(
    const uint4* __restrict__ Mb, const uint4* __restrict__ Wf,
    const float* __restrict__ bias, const float* __restrict__ c_dst,
    const float* __restrict__ c_src, unsigned short* __restrict__ out_bf,
    float* __restrict__ out_f32, int last)
{
    int tid = threadIdx.x;
    int wave = tid >> 6, lane = tid & 63;
    int quad = lane >> 4, m16 = lane & 15;
    int r0 = blockIdx.x * 64 + wave * 16;

    int rA = r0 + m16; if (rA >= N_NODES) rA = N_NODES - 1;
    union U { uint4 u; short8 s; };
    U a[4];
#pragma unroll
    for (int s = 0; s < 4; ++s)
        a[s].u = Mb[(size_t)s * (N_NODES * 4) + rA * 4 + quad];

    floatx4 acc[8];
#pragma unroll
    for (int c = 0; c < 8; ++c) {
        floatx4 ac = {0.f, 0.f, 0.f, 0.f};
#pragma unroll
        for (int s = 0; s < 4; ++s) {
            U b; b.u = Wf[(c * 4 + s) * 64 + lane];
            ac = __builtin_amdgcn_mfma_f32_16x16x32_bf16(a[s].s, b.s, ac, 0, 0, 0);
        }
        acc[c] = ac;
    }

    float cd[4], cs[4];
    int rows[4];
#pragma unroll
    for (int r = 0; r < 4; ++r) {
        int row = r0 + quad * 4 + r; rows[r] = row;
        bool ok = row < N_NODES;
        cd[r] = ok ? c_dst[row] : 0.f;
        cs[r] = (ok && !last) ? c_src[row] : 1.f;
    }
#pragma unroll
    for (int c = 0; c < 8; ++c) {
        int colg = c * 16 + m16;
        float b = bias[colg];
#pragma unroll
        for (int r = 0; r < 4; ++r) {
            int row = rows[r];
            if (row >= N_NODES) continue;
            float v = acc[c][r] * cd[r] + b;
            v = v > 0.f ? v : 0.f;
            if (last) out_f32[(size_t)row * DIM + colg] = v;
            else {
                int cho = colg >> 5;   // chunk-major bf16 write for next aggregate
                out_bf[(size_t)cho * (N_NODES * 32) + row * 32 + (colg & 31)] =
                    (unsigned short)f2bf(v * cs[r]);
            }
        }
    }
}

// Mean-pool readout on sorted graph_ids (fp32 h).
__global__ __launch_bounds__(128) void readout_kernel(
    const float* __restrict__ h, const int* __restrict__ gid,
    float* __restrict__ hg, float* __restrict__ cntg)
{
    int j  = threadIdx.x;
    int n0 = blockIdx.x * 64;
    float acc = 0.f; int cur = -1; int run = 0;
    for (int i = 0; i < 64; ++i) {
        int n = n0 + i;
        if (n >= N_NODES) break;
        int g = gid[n];
        if (g != cur) {
            if (cur >= 0) {
                atomicAdd(&hg[cur * DIM + j], acc);
                if (j == 0) atomicAdd(&cntg[cur], (float)run);
            }
            cur = g; acc = 0.f; run = 0;
        }
        acc += h[(size_t)n * DIM + j];
        run++;
    }
    if (cur >= 0) {
        atomicAdd(&hg[cur * DIM + j], acc);
        if (j == 0) atomicAdd(&cntg[cur], (float)run);
    }
}

__global__ __launch_bounds__(256) void head_kernel(
    const float* __restrict__ hg, const float* __restrict__ cntg,
    const float* __restrict__ Wc, const float* __restrict__ bc,
    float* __restrict__ out)
{
    int idx = blockIdx.x * blockDim.x + threadIdx.x;
    if (idx >= NGRAPH * NCLASS) return;
    int g = idx / NCLASS, c = idx % NCLASS;
    float inv = 1.0f / fmaxf(cntg[g], 1.0f);
    float s = 0.f;
    for (int j = 0; j < DIM; ++j) s = fmaf(hg[g * DIM + j], Wc[j * NCLASS + c], s);
    out[idx] = s * inv + bc[c];
}

// ---------------------------------------------------------------------------
extern "C" void kernel_launch(void* const* d_in, const int* in_sizes, int n_in,
                              void* d_out, int out_size, void* d_ws, size_t ws_size,
                              hipStream_t stream)
{
    const float* x   = (const float*)d_in[0];
    const float* W0  = (const float*)d_in[1];
    const float* b0  = (const float*)d_in[2];
    const float* Ws  = (const float*)d_in[3];
    const float* bs  = (const float*)d_in[4];
    const float* Wc  = (const float*)d_in[5];
    const float* bc  = (const float*)d_in[6];
    const int*   ei  = (const int*)d_in[7];
    const int*   gid = (const int*)d_in[8];
    float* out = (float*)d_out;

    char* ws = (char*)d_ws;
    size_t o = 0;
    auto alloc = [&](size_t bytes) {
        size_t r = o; o = (o + bytes + 255) & ~(size_t)255; return r;
    };
    unsigned* cntw      = (unsigned*)(ws + alloc((size_t)TEAMS * CWORDS * 4));
    unsigned* offsw     = (unsigned*)(ws + alloc((size_t)TEAMS * CWORDS * 4));
    unsigned* cnt_dense = (unsigned*)(ws + alloc((size_t)N_NODES * 4));
    float*    c_src     = (float*)(ws + alloc((size_t)N_NODES * 4));
    float*    c_dst     = (float*)(ws + alloc((size_t)N_NODES * 4));
    unsigned short* colc = (unsigned short*)(ws + alloc((size_t)N_NODES * 64 * 2));
    unsigned* hs        = (unsigned*)(ws + alloc((size_t)N_NODES * 64 * 4));
    unsigned* mbuf      = (unsigned*)(ws + alloc((size_t)N_NODES * 64 * 4));
    float*    hlast     = (float*)(ws + alloc((size_t)N_NODES * DIM * 4));
    uint4*    Wf        = (uint4*)(ws + alloc((size_t)NLAYER * 2048 * 16));
    float*    hg        = (float*)(ws + alloc((size_t)NGRAPH * DIM * 4));
    float*    cntg      = (float*)(ws + alloc((size_t)NGRAPH * 4));

    hipMemsetAsync(hg,   0, (size_t)NGRAPH * DIM * 4, stream);
    hipMemsetAsync(cntg, 0, (size_t)NGRAPH * 4, stream);

    count_kernel<<<TEAMS, 1024, 0, stream>>>(ei, cntw);
    offsets_kernel<<<(N_NODES + 255) / 256, 1024, 0, stream>>>(
        cntw, offsw, cnt_dense, c_src, c_dst);
    scatter_kernel<<<TEAMS, 1024, 0, stream>>>(ei, offsw, colc);
    prescale_kernel<<<(N_NODES * 64) / 256, 256, 0, stream>>>(
        (const float2*)x, c_src, hs);
    wprep_kernel<<<(NLAYER * 2048 + 255) / 256, 256, 0, stream>>>(W0, Ws, Wf);

    const int AGG_BLOCKS = 2048;   // 8 groups of 256 blocks (one per XCD)
    const int GEMM_BLOCKS = (N_NODES + 63) / 64;

    for (int l = 0; l < NLAYER; ++l) {
        const float* b = (l == 0) ? b0 : (bs + (size_t)(l - 1) * DIM);
        int last = (l == NLAYER - 1) ? 1 : 0;
        aggregate_kernel<<<AGG_BLOCKS, 256, 0, stream>>>(
            hs, colc, cnt_dense, mbuf);
        mfma_gemm_kernel<<<GEMM_BLOCKS, 256, 0, stream>>>(
            (const uint4*)mbuf, Wf + (size_t)l * 2048, b, c_dst, c_src,
            (unsigned short*)hs, hlast, last);
    }

    readout_kernel<<<(N_NODES + 63) / 64, 128, 0, stream>>>(hlast, gid, hg, cntg);
    head_kernel<<<(NGRAPH * NCLASS + 255) / 256, 256, 0, stream>>>(hg, cntg, Wc, bc, out);
}

// Round 2
// 354.469 us; speedup vs baseline: 1.3155x; 1.3155x over previous
//
#include <hip/hip_runtime.h>

#define N_NODES 50000
#define N_EDGES 800000
#define DIM     128
#define NGRAPH  128
#define NCLASS  10
#define NLAYER  4

#define TEAMS   256
#define ESLICE  (N_EDGES / TEAMS)    // 3125 edges per team slice
#define CWORDS  12500                // 50000 nodes / 4 (nibble-packed bytes per word)
#define NSLICE  (N_NODES / 8)        // 6250 nodes per XCD slice

typedef __attribute__((ext_vector_type(8))) short short8;
typedef __attribute__((ext_vector_type(4))) float floatx4;

__device__ __forceinline__ unsigned f2bf(float f) {
    union { float f; unsigned u; } v; v.f = f;
    return (v.u + 0x7fffu + ((v.u >> 16) & 1u)) >> 16;   // RNE
}
__device__ __forceinline__ float bf_lo(unsigned u) { return __uint_as_float(u << 16); }
__device__ __forceinline__ float bf_hi(unsigned u) { return __uint_as_float(u & 0xffff0000u); }

// ---------------------------------------------------------------------------
// Pass 1: per-team-slice nibble histograms (in=low nibble, out=high nibble,
// one byte per node). Each edge read exactly once. Coalesced writeback.
__global__ __launch_bounds__(1024) void count_kernel(
    const int* __restrict__ ei, unsigned* __restrict__ cntw)
{
    __shared__ unsigned h[CWORDS];      // 50 KB
    int team = blockIdx.x, tid = threadIdx.x;
    for (int i = tid; i < CWORDS; i += 1024) h[i] = 0;
    __syncthreads();
    const int e0 = team * ESLICE;
    const int* __restrict__ srcp = ei;
    const int* __restrict__ dstp = ei + N_EDGES;
    for (int e = e0 + tid; e < e0 + ESLICE; e += 1024) {
        int s = srcp[e], d = dstp[e];
        atomicAdd(&h[d >> 2], 1u  << (8 * (d & 3)));   // in-count  (low nibble)
        atomicAdd(&h[s >> 2], 16u << (8 * (s & 3)));   // out-count (high nibble)
    }
    __syncthreads();
    for (int i = tid; i < CWORDS; i += 1024)
        cntw[(size_t)team * CWORDS + i] = h[i];
}

// Pass 2: per-node exclusive prefix over the 256 team counts -> exact slot
// offsets; also emits total degrees -> cnt_dense, c_src, c_dst.
__global__ __launch_bounds__(1024) void offsets_kernel(
    const unsigned* __restrict__ cntw, unsigned* __restrict__ offsw,
    unsigned* __restrict__ cnt_dense, float* __restrict__ c_src,
    float* __restrict__ c_dst)
{
    __shared__ unsigned ldsC[128 * 64];   // counts tile
    __shared__ unsigned ldsO[128 * 64];   // offsets tile
    int tid = threadIdx.x;
    int n0 = blockIdx.x * 256;
    int w0 = n0 >> 2;
    unsigned indeg = 0, outdeg = 0;
    for (int ph = 0; ph < 2; ++ph) {
        int t0 = ph * 128;
        for (int i = tid; i < 128 * 64; i += 1024) {
            int tl = i >> 6, wl = i & 63;
            int gw = w0 + wl;
            ldsC[i] = (gw < CWORDS) ? cntw[(size_t)(t0 + tl) * CWORDS + gw] : 0u;
        }
        __syncthreads();
        if (tid < 256) {
            unsigned char* ob = (unsigned char*)ldsO;
            for (int tl = 0; tl < 128; ++tl) {
                unsigned wv = ldsC[tl * 64 + (tid >> 2)];
                unsigned b = (wv >> (8 * (tid & 3))) & 255u;
                ob[tl * 256 + tid] = (unsigned char)indeg;  // exclusive prefix
                indeg  += (b & 15u);
                outdeg += (b >> 4);
            }
        }
        __syncthreads();
        for (int i = tid; i < 128 * 64; i += 1024) {
            int tl = i >> 6, wl = i & 63;
            int gw = w0 + wl;
            if (gw < CWORDS) offsw[(size_t)(t0 + tl) * CWORDS + gw] = ldsO[i];
        }
        __syncthreads();
    }
    if (tid < 256) {
        int n = n0 + tid;
        if (n < N_NODES) {
            unsigned id_ = indeg, od = outdeg;
            cnt_dense[n] = id_ > 64u ? 64u : id_;
            if (id_ < 1u) id_ = 1u;
            if (od < 1u) od = 1u;
            c_dst[n] = 1.0f / sqrtf((float)id_);
            c_src[n] = 1.0f / sqrtf((float)od);
        }
    }
}

// Pass 3: rescan slice, LDS position counters give unique local pos; write
// src directly into dense CSR at offs(team,d)+pos. colc is ushort (N<65536).
__global__ __launch_bounds__(1024) void scatter_kernel(
    const int* __restrict__ ei, const unsigned* __restrict__ offsw,
    unsigned short* __restrict__ colc)
{
    __shared__ unsigned h[CWORDS];      // 50 KB pos counters (low nibble)
    int team = blockIdx.x, tid = threadIdx.x;
    for (int i = tid; i < CWORDS; i += 1024) h[i] = 0;
    __syncthreads();
    const unsigned char* __restrict__ ob =
        (const unsigned char*)offsw + (size_t)team * 50000;
    const int e0 = team * ESLICE;
    const int* __restrict__ srcp = ei;
    const int* __restrict__ dstp = ei + N_EDGES;
    for (int e = e0 + tid; e < e0 + ESLICE; e += 1024) {
        int s = srcp[e], d = dstp[e];
        unsigned old = atomicAdd(&h[d >> 2], 1u << (8 * (d & 3)));
        unsigned pos = (old >> (8 * (d & 3))) & 15u;
        unsigned slot = (unsigned)ob[d] + pos;
        if (slot < 64u) colc[(size_t)d * 64 + slot] = (unsigned short)s;
    }
}

// hs(bf16 pairs, node-major) = x * c_src[row]
__global__ __launch_bounds__(256) void prescale_kernel(
    const float2* __restrict__ x, const float* __restrict__ c_src,
    unsigned* __restrict__ hs)
{
    int i = blockIdx.x * blockDim.x + threadIdx.x;   // over N*64 uints
    if (i >= N_NODES * 64) return;
    int row = i >> 6;
    float c = c_src[row];
    float2 v = x[i];
    hs[i] = f2bf(v.x * c) | (f2bf(v.y * c) << 16);
}

// m[n] = sum over in-edges of hs[src]. Wave per node, full 128-feat row:
// lane half (32 lanes) covers edge parity, hl = feature quad (uint2 = 4
// feats, 256 B per row split across the half). 8-deep k-unroll -> one
// dependent load chain for deg<=16 (the mean). 32-bit byte offsets from a
// uniform base -> saddr-form loads (1 VALU addr op). XCD node slices keep
// colc/m local; hs gathers hit L2/L3.
__global__ __launch_bounds__(256) void aggregate_kernel(
    const unsigned* __restrict__ hs, const unsigned short* __restrict__ colc,
    const unsigned* __restrict__ cnt_dense, unsigned* __restrict__ m)
{
    int b = blockIdx.x;
    int slice = b & 7;                              // intended XCD id
    int wid = (b >> 3) * 4 + (threadIdx.x >> 6);    // 0..1023 within slice
    int lane = threadIdx.x & 63;
    int half = lane >> 5;          // 0: even edges, 1: odd edges
    int hl   = lane & 31;          // feature quad: features 4*hl .. 4*hl+3
    unsigned hoff = (unsigned)(hl << 3);            // byte offset in row
    const char* __restrict__ hb = (const char*)hs;
    int nbeg = slice * NSLICE, nend = nbeg + NSLICE;
    for (int n = nbeg + wid; n < nend; n += 1024) {
        unsigned deg = cnt_dense[n];
        int myidx = (int)__builtin_nontemporal_load(&colc[(unsigned)n * 64u + (unsigned)lane]);
        float f0 = 0.f, f1 = 0.f, f2 = 0.f, f3 = 0.f;
        for (unsigned j = 0; j < deg; j += 16) {
#pragma unroll
            for (int k = 0; k < 8; ++k) {
                unsigned e = j + 2u * (unsigned)k + (unsigned)half;
                int sl = (e < deg) ? (int)e : 0;   // slot 0 valid when deg>0
                int s = __shfl(myidx, sl);
                uint2 u = *(const uint2*)(hb + (((unsigned)s << 8) + hoff));
                if (e >= deg) { u.x = 0u; u.y = 0u; }
                f0 += bf_lo(u.x); f1 += bf_hi(u.x);
                f2 += bf_lo(u.y); f3 += bf_hi(u.y);
            }
        }
        f0 += __shfl_xor(f0, 32); f1 += __shfl_xor(f1, 32);
        f2 += __shfl_xor(f2, 32); f3 += __shfl_xor(f3, 32);
        if (half == 0) {
            uint2 r;
            r.x = f2bf(f0) | (f2bf(f1) << 16);
            r.y = f2bf(f2) | (f2bf(f3) << 16);
            *(uint2*)((char*)m + (((unsigned)n << 8) + hoff)) = r;
        }
    }
}

// Pre-swizzle W into MFMA B-fragment order, bf16.
__global__ __launch_bounds__(256) void wprep_kernel(
    const float* __restrict__ W0, const float* __restrict__ Ws,
    uint4* __restrict__ Wf)
{
    int t = blockIdx.x * blockDim.x + threadIdx.x;
    if (t >= NLAYER * 2048) return;
    int layer = t >> 11;
    int rem = t & 2047;
    int lane = rem & 63;
    int s = (rem >> 6) & 3;
    int c = rem >> 8;
    int quad = lane >> 4, colw = c * 16 + (lane & 15);
    int k0 = s * 32 + quad * 8;
    const float* W = (layer == 0) ? W0 : Ws + (size_t)(layer - 1) * DIM * DIM;
    uint4 p;
    unsigned* pp = (unsigned*)&p;
#pragma unroll
    for (int j = 0; j < 4; ++j) {
        unsigned lo = f2bf(W[(size_t)(k0 + 2 * j) * DIM + colw]);
        unsigned hi = f2bf(W[(size_t)(k0 + 2 * j + 1) * DIM + colw]);
        pp[j] = lo | (hi << 16);
    }
    Wf[t] = p;
}

// Hout = relu(c_dst[r]*(M@W) + b) [* c_src[r] if !last], MFMA 16x16x32 bf16.
__global__ __launch_bounds__(256) void mfma_gemm_kernel(
    const uint4* __restrict__ Mb, const uint4* __restrict__ Wf,
    const float* __restrict__ bias, const float* __restrict__ c_dst,
    const float* __restrict__ c_src, unsigned short* __restrict__ out_bf,
    float* __restrict__ out_f32, int last)
{
    int tid = threadIdx.x;
    int wave = tid >> 6, lane = tid & 63;
    int quad = lane >> 4, m16 = lane & 15;
    int r0 = blockIdx.x * 64 + wave * 16;

    int rA = r0 + m16; if (rA >= N_NODES) rA = N_NODES - 1;
    const uint4* pA = Mb + (size_t)rA * 16 + quad;
    union U { uint4 u; short8 s; };
    U a[4];
#pragma unroll
    for (int s = 0; s < 4; ++s) a[s].u = pA[s * 4];

    floatx4 acc[8];
#pragma unroll
    for (int c = 0; c < 8; ++c) {
        floatx4 ac = {0.f, 0.f, 0.f, 0.f};
#pragma unroll
        for (int s = 0; s < 4; ++s) {
            U b; b.u = Wf[(c * 4 + s) * 64 + lane];
            ac = __builtin_amdgcn_mfma_f32_16x16x32_bf16(a[s].s, b.s, ac, 0, 0, 0);
        }
        acc[c] = ac;
    }

    float cd[4], cs[4];
    int rows[4];
#pragma unroll
    for (int r = 0; r < 4; ++r) {
        int row = r0 + quad * 4 + r; rows[r] = row;
        bool ok = row < N_NODES;
        cd[r] = ok ? c_dst[row] : 0.f;
        cs[r] = (ok && !last) ? c_src[row] : 1.f;
    }
#pragma unroll
    for (int c = 0; c < 8; ++c) {
        int colg = c * 16 + m16;
        float b = bias[colg];
#pragma unroll
        for (int r = 0; r < 4; ++r) {
            int row = rows[r];
            if (row >= N_NODES) continue;
            float v = acc[c][r] * cd[r] + b;
            v = v > 0.f ? v : 0.f;
            if (last) out_f32[(size_t)row * DIM + colg] = v;
            else      out_bf[(size_t)row * DIM + colg] = (unsigned short)f2bf(v * cs[r]);
        }
    }
}

// Mean-pool readout on sorted graph_ids (fp32 h).
__global__ __launch_bounds__(128) void readout_kernel(
    const float* __restrict__ h, const int* __restrict__ gid,
    float* __restrict__ hg, float* __restrict__ cntg)
{
    int j  = threadIdx.x;
    int n0 = blockIdx.x * 64;
    float acc = 0.f; int cur = -1; int run = 0;
    for (int i = 0; i < 64; ++i) {
        int n = n0 + i;
        if (n >= N_NODES) break;
        int g = gid[n];
        if (g != cur) {
            if (cur >= 0) {
                atomicAdd(&hg[cur * DIM + j], acc);
                if (j == 0) atomicAdd(&cntg[cur], (float)run);
            }
            cur = g; acc = 0.f; run = 0;
        }
        acc += h[(size_t)n * DIM + j];
        run++;
    }
    if (cur >= 0) {
        atomicAdd(&hg[cur * DIM + j], acc);
        if (j == 0) atomicAdd(&cntg[cur], (float)run);
    }
}

__global__ __launch_bounds__(256) void head_kernel(
    const float* __restrict__ hg, const float* __restrict__ cntg,
    const float* __restrict__ Wc, const float* __restrict__ bc,
    float* __restrict__ out)
{
    int idx = blockIdx.x * blockDim.x + threadIdx.x;
    if (idx >= NGRAPH * NCLASS) return;
    int g = idx / NCLASS, c = idx % NCLASS;
    float inv = 1.0f / fmaxf(cntg[g], 1.0f);
    float s = 0.f;
    for (int j = 0; j < DIM; ++j) s = fmaf(hg[g * DIM + j], Wc[j * NCLASS + c], s);
    out[idx] = s * inv + bc[c];
}

// ---------------------------------------------------------------------------
extern "C" void kernel_launch(void* const* d_in, const int* in_sizes, int n_in,
                              void* d_out, int out_size, void* d_ws, size_t ws_size,
                              hipStream_t stream)
{
    const float* x   = (const float*)d_in[0];
    const float* W0  = (const float*)d_in[1];
    const float* b0  = (const float*)d_in[2];
    const float* Ws  = (const float*)d_in[3];
    const float* bs  = (const float*)d_in[4];
    const float* Wc  = (const float*)d_in[5];
    const float* bc  = (const float*)d_in[6];
    const int*   ei  = (const int*)d_in[7];
    const int*   gid = (const int*)d_in[8];
    float* out = (float*)d_out;

    char* ws = (char*)d_ws;
    size_t o = 0;
    auto alloc = [&](size_t bytes) {
        size_t r = o; o = (o + bytes + 255) & ~(size_t)255; return r;
    };
    unsigned* cntw      = (unsigned*)(ws + alloc((size_t)TEAMS * CWORDS * 4));
    unsigned* offsw     = (unsigned*)(ws + alloc((size_t)TEAMS * CWORDS * 4));
    unsigned* cnt_dense = (unsigned*)(ws + alloc((size_t)N_NODES * 4));
    float*    c_src     = (float*)(ws + alloc((size_t)N_NODES * 4));
    float*    c_dst     = (float*)(ws + alloc((size_t)N_NODES * 4));
    unsigned short* colc = (unsigned short*)(ws + alloc((size_t)N_NODES * 64 * 2));
    unsigned* hs        = (unsigned*)(ws + alloc((size_t)N_NODES * 64 * 4));
    unsigned* mbuf      = (unsigned*)(ws + alloc((size_t)N_NODES * 64 * 4));
    float*    hlast     = (float*)(ws + alloc((size_t)N_NODES * DIM * 4));
    uint4*    Wf        = (uint4*)(ws + alloc((size_t)NLAYER * 2048 * 16));
    float*    hg        = (float*)(ws + alloc((size_t)NGRAPH * DIM * 4));
    float*    cntg      = (float*)(ws + alloc((size_t)NGRAPH * 4));

    hipMemsetAsync(hg,   0, (size_t)NGRAPH * DIM * 4, stream);
    hipMemsetAsync(cntg, 0, (size_t)NGRAPH * 4, stream);

    count_kernel<<<TEAMS, 1024, 0, stream>>>(ei, cntw);
    offsets_kernel<<<(N_NODES + 255) / 256, 1024, 0, stream>>>(
        cntw, offsw, cnt_dense, c_src, c_dst);
    scatter_kernel<<<TEAMS, 1024, 0, stream>>>(ei, offsw, colc);
    prescale_kernel<<<(N_NODES * 64) / 256, 256, 0, stream>>>(
        (const float2*)x, c_src, hs);
    wprep_kernel<<<(NLAYER * 2048 + 255) / 256, 256, 0, stream>>>(W0, Ws, Wf);

    const int AGG_BLOCKS = 2048;   // 8 XCD slices x 256 blocks
    const int GEMM_BLOCKS = (N_NODES + 63) / 64;

    for (int l = 0; l < NLAYER; ++l) {
        const float* b = (l == 0) ? b0 : (bs + (size_t)(l - 1) * DIM);
        int last = (l == NLAYER - 1) ? 1 : 0;
        aggregate_kernel<<<AGG_BLOCKS, 256, 0, stream>>>(
            hs, colc, cnt_dense, mbuf);
        mfma_gemm_kernel<<<GEMM_BLOCKS, 256, 0, stream>>>(
            (const uint4*)mbuf, Wf + (size_t)l * 2048, b, c_dst, c_src,
            (unsigned short*)hs, hlast, last);
    }

    readout_kernel<<<(N_NODES + 63) / 64, 128, 0, stream>>>(hlast, gid, hg, cntg);
    head_kernel<<<(NGRAPH * NCLASS + 255) / 256, 256, 0, stream>>>(hg, cntg, Wc, bc, out);
}

// Round 3
// 284.900 us; speedup vs baseline: 1.6368x; 1.2442x over previous
//
#include <hip/hip_runtime.h>

#define N_NODES 50000
#define N_EDGES 800000
#define DIM     128
#define NGRAPH  128
#define NCLASS  10
#define NLAYER  4

#define TEAMS   256
#define ESLICE  (N_EDGES / TEAMS)    // 3125 edges per team slice
#define CWORDS  12500                // 50000 nodes / 4 (nibble-packed bytes per word)
#define DUMMY   50000                // pad node id; hs row 50000 is all-zero
#define PRE_BLOCKS 12501             // ceil((N+1)*64 / 256) for prescale part

typedef __attribute__((ext_vector_type(8))) short short8;
typedef __attribute__((ext_vector_type(4))) float floatx4;

__device__ __forceinline__ unsigned f2bf(float f) {
    union { float f; unsigned u; } v; v.f = f;
    return (v.u + 0x7fffu + ((v.u >> 16) & 1u)) >> 16;   // RNE
}
__device__ __forceinline__ float bf_lo(unsigned u) { return __uint_as_float(u << 16); }
__device__ __forceinline__ float bf_hi(unsigned u) { return __uint_as_float(u & 0xffff0000u); }

// ---------------------------------------------------------------------------
// Pass 1: per-team-slice nibble histograms (in=low nibble, out=high nibble,
// one byte per node). Tail: pre-fill colc with DUMMY ids so the gather needs
// no per-edge masking (dummy slots read the all-zero hs row).
__global__ __launch_bounds__(1024) void count_kernel(
    const int* __restrict__ ei, unsigned* __restrict__ cntw,
    unsigned* __restrict__ colc_fill)
{
    __shared__ unsigned h[CWORDS];      // 50 KB
    int team = blockIdx.x, tid = threadIdx.x;
    for (int i = tid; i < CWORDS; i += 1024) h[i] = 0;
    __syncthreads();
    const int e0 = team * ESLICE;
    const int* __restrict__ srcp = ei;
    const int* __restrict__ dstp = ei + N_EDGES;
    for (int e = e0 + tid; e < e0 + ESLICE; e += 1024) {
        int s = srcp[e], d = dstp[e];
        atomicAdd(&h[d >> 2], 1u  << (8 * (d & 3)));   // in-count  (low nibble)
        atomicAdd(&h[s >> 2], 16u << (8 * (s & 3)));   // out-count (high nibble)
    }
    __syncthreads();
    for (int i = tid; i < CWORDS; i += 1024)
        cntw[(size_t)team * CWORDS + i] = h[i];
    // fill colc (as uints) with 0xC350C350 = two ushort DUMMYs
    for (int i = blockIdx.x * 1024 + tid; i < N_NODES * 32; i += TEAMS * 1024)
        colc_fill[i] = 0xC350C350u;
}

// Pass 2: per-node exclusive prefix over the 256 team counts -> exact slot
// offsets; also emits total degrees -> cnt_dense, c_src, c_dst.
__global__ __launch_bounds__(1024) void offsets_kernel(
    const unsigned* __restrict__ cntw, unsigned* __restrict__ offsw,
    unsigned* __restrict__ cnt_dense, float* __restrict__ c_src,
    float* __restrict__ c_dst)
{
    __shared__ unsigned ldsC[128 * 64];   // counts tile
    __shared__ unsigned ldsO[128 * 64];   // offsets tile
    int tid = threadIdx.x;
    int n0 = blockIdx.x * 256;
    int w0 = n0 >> 2;
    unsigned indeg = 0, outdeg = 0;
    for (int ph = 0; ph < 2; ++ph) {
        int t0 = ph * 128;
        for (int i = tid; i < 128 * 64; i += 1024) {
            int tl = i >> 6, wl = i & 63;
            int gw = w0 + wl;
            ldsC[i] = (gw < CWORDS) ? cntw[(size_t)(t0 + tl) * CWORDS + gw] : 0u;
        }
        __syncthreads();
        if (tid < 256) {
            unsigned char* ob = (unsigned char*)ldsO;
            for (int tl = 0; tl < 128; ++tl) {
                unsigned wv = ldsC[tl * 64 + (tid >> 2)];
                unsigned b = (wv >> (8 * (tid & 3))) & 255u;
                ob[tl * 256 + tid] = (unsigned char)indeg;  // exclusive prefix
                indeg  += (b & 15u);
                outdeg += (b >> 4);
            }
        }
        __syncthreads();
        for (int i = tid; i < 128 * 64; i += 1024) {
            int tl = i >> 6, wl = i & 63;
            int gw = w0 + wl;
            if (gw < CWORDS) offsw[(size_t)(t0 + tl) * CWORDS + gw] = ldsO[i];
        }
        __syncthreads();
    }
    if (tid < 256) {
        int n = n0 + tid;
        if (n < N_NODES) {
            unsigned id_ = indeg, od = outdeg;
            cnt_dense[n] = id_ > 64u ? 64u : id_;
            if (id_ < 1u) id_ = 1u;
            if (od < 1u) od = 1u;
            c_dst[n] = 1.0f / sqrtf((float)id_);
            c_src[n] = 1.0f / sqrtf((float)od);
        }
    }
}

// Pass 3: rescan slice, LDS position counters give unique local pos; write
// src directly into dense CSR at offs(team,d)+pos. colc is ushort (N<65536).
__global__ __launch_bounds__(1024) void scatter_kernel(
    const int* __restrict__ ei, const unsigned* __restrict__ offsw,
    unsigned short* __restrict__ colc)
{
    __shared__ unsigned h[CWORDS];      // 50 KB pos counters (low nibble)
    int team = blockIdx.x, tid = threadIdx.x;
    for (int i = tid; i < CWORDS; i += 1024) h[i] = 0;
    __syncthreads();
    const unsigned char* __restrict__ ob =
        (const unsigned char*)offsw + (size_t)team * 50000;
    const int e0 = team * ESLICE;
    const int* __restrict__ srcp = ei;
    const int* __restrict__ dstp = ei + N_EDGES;
    for (int e = e0 + tid; e < e0 + ESLICE; e += 1024) {
        int s = srcp[e], d = dstp[e];
        unsigned old = atomicAdd(&h[d >> 2], 1u << (8 * (d & 3)));
        unsigned pos = (old >> (8 * (d & 3))) & 15u;
        unsigned slot = (unsigned)ob[d] + pos;
        if (slot < 64u) colc[(size_t)d * 64 + slot] = (unsigned short)s;
    }
}

// prescale (hsA = x * c_src, row DUMMY zeroed in BOTH hs buffers) + wprep
// (W -> MFMA B-fragment bf16) merged into one dispatch.
__global__ __launch_bounds__(256) void prep_kernel(
    const float2* __restrict__ x, const float* __restrict__ c_src,
    unsigned* __restrict__ hsA, unsigned* __restrict__ hsB,
    const float* __restrict__ W0, const float* __restrict__ Ws,
    uint4* __restrict__ Wf)
{
    int bid = blockIdx.x;
    if (bid < PRE_BLOCKS) {
        int i = bid * 256 + threadIdx.x;    // over (N+1)*64 uints
        if (i >= (N_NODES + 1) * 64) return;
        int row = i >> 6;
        if (row < N_NODES) {
            float c = c_src[row];
            float2 v = x[i];
            hsA[i] = f2bf(v.x * c) | (f2bf(v.y * c) << 16);
        } else {
            hsA[i] = 0u;    // dummy row stays zero through all layers:
            hsB[i] = 0u;    // layer epilogues only write rows < N_NODES
        }
        return;
    }
    int t = (bid - PRE_BLOCKS) * 256 + threadIdx.x;
    if (t >= NLAYER * 2048) return;
    int layer = t >> 11;
    int rem = t & 2047;
    int lane = rem & 63;
    int s = (rem >> 6) & 3;
    int c = rem >> 8;
    int quad = lane >> 4, colw = c * 16 + (lane & 15);
    int k0 = s * 32 + quad * 8;
    const float* W = (layer == 0) ? W0 : Ws + (size_t)(layer - 1) * DIM * DIM;
    uint4 p;
    unsigned* pp = (unsigned*)&p;
#pragma unroll
    for (int j = 0; j < 4; ++j) {
        unsigned lo = f2bf(W[(size_t)(k0 + 2 * j) * DIM + colw]);
        unsigned hi = f2bf(W[(size_t)(k0 + 2 * j + 1) * DIM + colw]);
        pp[j] = lo | (hi << 16);
    }
    Wf[t] = p;
}

// Fused conv layer: block = 256 threads = 4 waves owns 16 rows.
// Phase A: wave w aggregates nodes r0+w*4+i (i=0..3): wave-per-node gather
//   (half = edge parity, hl = feature quad), no masking (dummy pad), 1-level
//   shfl_xor reduce, bf16 pack -> LDS A-tile (XOR-swizzled, 2-way = free).
// Phase B: each wave MFMAs the 16-row tile over 2 of 8 column blocks.
// hs double-buffered across layers (in != out) to avoid cross-block races.
__global__ __launch_bounds__(256) void layer_kernel(
    const unsigned* __restrict__ hs, const unsigned short* __restrict__ colc,
    const unsigned* __restrict__ cnt_dense, const uint4* __restrict__ Wf,
    const float* __restrict__ bias, const float* __restrict__ c_dst,
    const float* __restrict__ c_src, unsigned short* __restrict__ out_bf,
    float* __restrict__ out_f32, int last)
{
    __shared__ unsigned Ash[16 * 64];    // 4 KB A-tile (16 rows x 256 B)
    char* Ab = (char*)Ash;
    int tid = threadIdx.x;
    int wave = tid >> 6, lane = tid & 63;
    int half = lane >> 5, hl = lane & 31;
    unsigned hoff = (unsigned)(hl << 3);
    const char* __restrict__ hb = (const char*)hs;
    int r0 = blockIdx.x * 16;            // 3125 * 16 = 50000 exactly

#pragma unroll
    for (int i = 0; i < 4; ++i) {
        int il = wave * 4 + i;
        int n = r0 + il;
        unsigned deg = cnt_dense[n];
        int myidx = (int)colc[(unsigned)n * 64u + (unsigned)lane];
        float f0 = 0.f, f1 = 0.f, f2 = 0.f, f3 = 0.f;
        for (unsigned j = 0; j < deg; j += 16) {
#pragma unroll
            for (int k = 0; k < 8; ++k) {
                int s = __shfl(myidx, (int)(j + 2u * k) + half);
                uint2 u = *(const uint2*)(hb + (((unsigned)s << 8) + hoff));
                f0 += bf_lo(u.x); f1 += bf_hi(u.x);
                f2 += bf_lo(u.y); f3 += bf_hi(u.y);
            }
        }
        f0 += __shfl_xor(f0, 32); f1 += __shfl_xor(f1, 32);
        f2 += __shfl_xor(f2, 32); f3 += __shfl_xor(f3, 32);
        if (half == 0) {
            uint2 r;
            r.x = f2bf(f0) | (f2bf(f1) << 16);
            r.y = f2bf(f2) | (f2bf(f3) << 16);
            *(uint2*)(Ab + il * 256 + ((hl * 8) ^ ((il & 7) << 4))) = r;
        }
    }
    __syncthreads();

    int quad = lane >> 4, m16 = lane & 15;
    union U { uint4 u; short8 s; };
    U a[4];
#pragma unroll
    for (int s = 0; s < 4; ++s)
        a[s].u = *(const uint4*)(
            Ab + m16 * 256 + ((s * 64 + quad * 16) ^ ((m16 & 7) << 4)));

    floatx4 acc[2];
#pragma unroll
    for (int cc = 0; cc < 2; ++cc) {
        int c = wave * 2 + cc;
        floatx4 ac = {0.f, 0.f, 0.f, 0.f};
#pragma unroll
        for (int s = 0; s < 4; ++s) {
            U b; b.u = Wf[(c * 4 + s) * 64 + lane];
            ac = __builtin_amdgcn_mfma_f32_16x16x32_bf16(a[s].s, b.s, ac, 0, 0, 0);
        }
        acc[cc] = ac;
    }

    float cd[4], cs[4];
#pragma unroll
    for (int r = 0; r < 4; ++r) {
        int row = r0 + quad * 4 + r;
        cd[r] = c_dst[row];
        cs[r] = last ? 1.f : c_src[row];
    }
#pragma unroll
    for (int cc = 0; cc < 2; ++cc) {
        int colg = (wave * 2 + cc) * 16 + m16;
        float b = bias[colg];
#pragma unroll
        for (int r = 0; r < 4; ++r) {
            int row = r0 + quad * 4 + r;
            float v = acc[cc][r] * cd[r] + b;
            v = v > 0.f ? v : 0.f;
            if (last) out_f32[(size_t)row * DIM + colg] = v;
            else      out_bf[(size_t)row * DIM + colg] = (unsigned short)f2bf(v * cs[r]);
        }
    }
}

// Mean-pool readout on sorted graph_ids (fp32 h).
__global__ __launch_bounds__(128) void readout_kernel(
    const float* __restrict__ h, const int* __restrict__ gid,
    float* __restrict__ hg, float* __restrict__ cntg)
{
    int j  = threadIdx.x;
    int n0 = blockIdx.x * 64;
    float acc = 0.f; int cur = -1; int run = 0;
    for (int i = 0; i < 64; ++i) {
        int n = n0 + i;
        if (n >= N_NODES) break;
        int g = gid[n];
        if (g != cur) {
            if (cur >= 0) {
                atomicAdd(&hg[cur * DIM + j], acc);
                if (j == 0) atomicAdd(&cntg[cur], (float)run);
            }
            cur = g; acc = 0.f; run = 0;
        }
        acc += h[(size_t)n * DIM + j];
        run++;
    }
    if (cur >= 0) {
        atomicAdd(&hg[cur * DIM + j], acc);
        if (j == 0) atomicAdd(&cntg[cur], (float)run);
    }
}

__global__ __launch_bounds__(256) void head_kernel(
    const float* __restrict__ hg, const float* __restrict__ cntg,
    const float* __restrict__ Wc, const float* __restrict__ bc,
    float* __restrict__ out)
{
    int idx = blockIdx.x * blockDim.x + threadIdx.x;
    if (idx >= NGRAPH * NCLASS) return;
    int g = idx / NCLASS, c = idx % NCLASS;
    float inv = 1.0f / fmaxf(cntg[g], 1.0f);
    float s = 0.f;
    for (int j = 0; j < DIM; ++j) s = fmaf(hg[g * DIM + j], Wc[j * NCLASS + c], s);
    out[idx] = s * inv + bc[c];
}

// ---------------------------------------------------------------------------
extern "C" void kernel_launch(void* const* d_in, const int* in_sizes, int n_in,
                              void* d_out, int out_size, void* d_ws, size_t ws_size,
                              hipStream_t stream)
{
    const float* x   = (const float*)d_in[0];
    const float* W0  = (const float*)d_in[1];
    const float* b0  = (const float*)d_in[2];
    const float* Ws  = (const float*)d_in[3];
    const float* bs  = (const float*)d_in[4];
    const float* Wc  = (const float*)d_in[5];
    const float* bc  = (const float*)d_in[6];
    const int*   ei  = (const int*)d_in[7];
    const int*   gid = (const int*)d_in[8];
    float* out = (float*)d_out;

    char* ws = (char*)d_ws;
    size_t o = 0;
    auto alloc = [&](size_t bytes) {
        size_t r = o; o = (o + bytes + 255) & ~(size_t)255; return r;
    };
    unsigned* cntw      = (unsigned*)(ws + alloc((size_t)TEAMS * CWORDS * 4));
    unsigned* offsw     = (unsigned*)(ws + alloc((size_t)TEAMS * CWORDS * 4));
    unsigned* cnt_dense = (unsigned*)(ws + alloc((size_t)N_NODES * 4));
    float*    c_src     = (float*)(ws + alloc((size_t)N_NODES * 4));
    float*    c_dst     = (float*)(ws + alloc((size_t)N_NODES * 4));
    unsigned short* colc = (unsigned short*)(ws + alloc((size_t)N_NODES * 64 * 2));
    unsigned* hsA       = (unsigned*)(ws + alloc((size_t)(N_NODES + 1) * 64 * 4));
    unsigned* hsB       = (unsigned*)(ws + alloc((size_t)(N_NODES + 1) * 64 * 4));
    float*    hlast     = (float*)(ws + alloc((size_t)N_NODES * DIM * 4));
    uint4*    Wf        = (uint4*)(ws + alloc((size_t)NLAYER * 2048 * 16));
    float*    hg        = (float*)(ws + alloc((size_t)NGRAPH * DIM * 4));
    float*    cntg      = (float*)(ws + alloc((size_t)NGRAPH * 4));

    hipMemsetAsync(hg,   0, (size_t)NGRAPH * DIM * 4, stream);
    hipMemsetAsync(cntg, 0, (size_t)NGRAPH * 4, stream);

    count_kernel<<<TEAMS, 1024, 0, stream>>>(ei, cntw, (unsigned*)colc);
    offsets_kernel<<<(N_NODES + 255) / 256, 1024, 0, stream>>>(
        cntw, offsw, cnt_dense, c_src, c_dst);
    scatter_kernel<<<TEAMS, 1024, 0, stream>>>(ei, offsw, colc);
    prep_kernel<<<PRE_BLOCKS + (NLAYER * 2048 + 255) / 256, 256, 0, stream>>>(
        (const float2*)x, c_src, hsA, hsB, W0, Ws, Wf);

    const int LAYER_BLOCKS = N_NODES / 16;   // 3125, exact

    for (int l = 0; l < NLAYER; ++l) {
        const float* b = (l == 0) ? b0 : (bs + (size_t)(l - 1) * DIM);
        int last = (l == NLAYER - 1) ? 1 : 0;
        const unsigned* hin = (l & 1) ? hsB : hsA;
        unsigned* hout      = (l & 1) ? hsA : hsB;
        layer_kernel<<<LAYER_BLOCKS, 256, 0, stream>>>(
            hin, colc, cnt_dense, Wf + (size_t)l * 2048, b, c_dst, c_src,
            (unsigned short*)hout, hlast, last);
    }

    readout_kernel<<<(N_NODES + 63) / 64, 128, 0, stream>>>(hlast, gid, hg, cntg);
    head_kernel<<<(NGRAPH * NCLASS + 255) / 256, 256, 0, stream>>>(hg, cntg, Wc, bc, out);
}